// Round 2
// baseline (1306.803 us; speedup 1.0000x reference)
//
#include <hip/hip_runtime.h>
#include <math.h>

#define N_NODES 32768
#define D_DIM 128
#define E_EDG 262144
#define M_MOT 131072
#define NG_G 32
#define F_TOT 896
// P slices: Q2 [0,128) K2 [128,256) Q3 [256,512) K3 [512,768) Qm [768,896)
// constants: lam2=1, lam3=0.5, lamm=1, b2=b3=bm=1 (softplus of stored raws)

__device__ __forceinline__ float wsum64(float v){
#pragma unroll
  for (int o = 32; o > 0; o >>= 1) v += __shfl_xor(v, o, 64);
  return v;
}

__device__ __forceinline__ unsigned f2key(float f){
  unsigned u = __float_as_uint(f);
  return (u & 0x80000000u) ? ~u : (u | 0x80000000u);
}
__device__ __forceinline__ float key2f(unsigned k){
  unsigned u = (k & 0x80000000u) ? (k & 0x7fffffffu) : ~k;
  return __uint_as_float(u);
}

__device__ __forceinline__ float bsum128(float v, float* scr, int t){
  float s = wsum64(v);
  if ((t & 63) == 0) scr[t >> 6] = s;
  __syncthreads();
  float r = scr[0] + scr[1];
  __syncthreads();
  return r;
}

// ---------------- prep ----------------
__global__ void k_prep_wcat(const float* wq2, const float* wk2, const float* wq3,
                            const float* wk3, const float* wqm,
                            float* Wcat, float* WcatT){
  int idx = blockIdx.x * 256 + threadIdx.x;
  if (idx >= F_TOT * D_DIM) return;
  int f = idx / D_DIM, d = idx - f * D_DIM;
  const float* src; int fr;
  if      (f < 128){ src = wq2; fr = f; }
  else if (f < 256){ src = wk2; fr = f - 128; }
  else if (f < 512){ src = wq3; fr = f - 256; }
  else if (f < 768){ src = wk3; fr = f - 512; }
  else             { src = wqm; fr = f - 768; }
  float v = src[fr * D_DIM + d];
  Wcat[f * D_DIM + d] = v;
  WcatT[d * F_TOT + f] = v;
}

__global__ void k_prep_km(const float* wkm, const float* bmem, float* Km){
  int idx = blockIdx.x * 256 + threadIdx.x; // H*K*HD = 4096
  if (idx >= 4096) return;
  int z = idx & 63, k = (idx >> 6) & 31, h = idx >> 11;
  const float* wrow = wkm + (h * 64 + z) * D_DIM;
  const float* brow = bmem + k * D_DIM;
  float acc = 0.f;
  for (int d = 0; d < D_DIM; d++) acc += wrow[d] * brow[d];
  Km[idx] = acc; // layout [h][k][z]
}

__global__ void k_init(unsigned* m2u, float* z2, unsigned* m3u, float* z3, float* Eg){
  int idx = blockIdx.x * 256 + threadIdx.x;
  if (idx < N_NODES * 2){ m2u[idx] = 0x007FFFFFu; z2[idx] = 0.f; m3u[idx] = 0x007FFFFFu; z3[idx] = 0.f; }
  if (idx < NG_G) Eg[idx] = 0.f;
}

// ---------------- layernorm forward ----------------
__global__ __launch_bounds__(128) void k_layernorm(const float* X, const float* gamma, const float* beta,
                            float* G, float* mu, float* rstd, float* e_node){
  __shared__ float scr[2];
  int n = blockIdx.x, t = threadIdx.x;
  float x = X[(size_t)n * D_DIM + t];
  float sumx = bsum128(x, scr, t);
  float m = sumx * (1.0f / D_DIM);
  float xm = x - m;
  float var = bsum128(xm * xm, scr, t) * (1.0f / D_DIM);
  float rs = rsqrtf(var + 1e-5f);
  G[(size_t)n * D_DIM + t] = gamma[t] * xm * rs + beta[t];
  float sxx = bsum128(x * x, scr, t);
  if (t == 0){ mu[n] = m; rstd[n] = rs; e_node[n] = 0.5f * sxx; }
}

// ---------------- forward projection GEMM: P[n,f] = sum_d G[n,d]*Wcat[f,d] ----------------
__global__ __launch_bounds__(256) void k_fwd_gemm(const float* G, const float* WcatT, float* P){
  __shared__ float Gs[8 * 128];
  int n0 = blockIdx.x * 8, t = threadIdx.x;
  for (int idx = t; idx < 8 * 128; idx += 256) Gs[idx] = G[(size_t)n0 * 128 + idx];
  __syncthreads();
  for (int fo = 0; fo < F_TOT; fo += 256){
    int f = fo + t;
    if (f < F_TOT){
      float acc[8] = {0,0,0,0,0,0,0,0};
      for (int d = 0; d < 128; d++){
        float w = WcatT[d * F_TOT + f];
#pragma unroll
        for (int i = 0; i < 8; i++) acc[i] += Gs[i * 128 + d] * w;
      }
#pragma unroll
      for (int i = 0; i < 8; i++) P[(size_t)(n0 + i) * F_TOT + f] = acc[i];
    }
  }
}

// ---------------- edges forward ----------------
__global__ __launch_bounds__(256) void k_edge_fwd(const float* P, const int* c2, const int* u2,
                    const float* a2, float* s2, unsigned* m2u){
  int e = blockIdx.x * 4 + (threadIdx.x >> 6);
  int z = threadIdx.x & 63;
  int c = c2[e], u = u2[e];
  const float* pc = P + (size_t)c * F_TOT;        // Q2
  const float* pu = P + (size_t)u * F_TOT + 128;  // K2
#pragma unroll
  for (int h = 0; h < 2; h++){
    float s = wsum64(pc[h * 64 + z] * pu[h * 64 + z]);
    if (z == 0){
      s = s * 0.125f + a2[(size_t)e * 2 + h];
      s2[(size_t)e * 2 + h] = s;
      atomicMax(&m2u[c * 2 + h], f2key(s));
    }
  }
}

__global__ void k_edge_z(const float* s2, const int* c2, const unsigned* m2u, float* z2){
  int idx = blockIdx.x * 256 + threadIdx.x;
  if (idx >= E_EDG * 2) return;
  int e = idx >> 1, h = idx & 1;
  int c = c2[e];
  float m = key2f(m2u[c * 2 + h]);
  atomicAdd(&z2[c * 2 + h], expf(s2[idx] - m));
}

// ---------------- motifs forward ----------------
__global__ __launch_bounds__(256) void k_motif_fwd(const float* P, const int* c3, const int* u3, const int* v3,
                     const int* tt, const float* Ttau, float* s3, float* qkb, float* tvb, unsigned* m3u){
  int m = blockIdx.x * 4 + (threadIdx.x >> 6);
  int z = threadIdx.x & 63;
  int c = c3[m], u = u3[m], v = v3[m], t = tt[m];
  const float* pq  = P + (size_t)c * F_TOT + 256; // Q3
  const float* pku = P + (size_t)u * F_TOT + 512; // K3 at u
  const float* pkv = P + (size_t)v * F_TOT + 512; // K3 at v
  const float* tb = Ttau + (size_t)t * 256;       // [h][r][z]
#pragma unroll
  for (int h = 0; h < 2; h++){
    float ssum = 0.f;
#pragma unroll
    for (int r = 0; r < 2; r++){
      int o = h * 128 + r * 64 + z;
      float qkr = wsum64(pq[o] * pku[o]);
      float tvr = wsum64(tb[(h * 2 + r) * 64 + z] * pkv[o]);
      if (z == 0){ qkb[((size_t)m * 2 + h) * 2 + r] = qkr; tvb[((size_t)m * 2 + h) * 2 + r] = tvr; }
      ssum += qkr * tvr;
    }
    float s = ssum * (1.0f / 64.0f);
    if (z == 0){ s3[(size_t)m * 2 + h] = s; atomicMax(&m3u[c * 2 + h], f2key(s)); }
  }
}

__global__ void k_motif_z(const float* s3, const int* c3, const unsigned* m3u, float* z3){
  int idx = blockIdx.x * 256 + threadIdx.x;
  if (idx >= M_MOT * 2) return;
  int m = idx >> 1, h = idx & 1;
  int c = c3[m];
  float mm = key2f(m3u[c * 2 + h]);
  atomicAdd(&z3[c * 2 + h], expf(s3[idx] - mm));
}

// ---------------- memory term: forward + backward fused (node-local) ----------------
__global__ __launch_bounds__(64) void k_mem(const float* P, const float* Km, float* dP, float* e_node){
  __shared__ float Qs[128];
  __shared__ float pmem[64];
  __shared__ float em[2];
  int n = blockIdx.x, t = threadIdx.x;
  Qs[t]      = P[(size_t)n * F_TOT + 768 + t];
  Qs[t + 64] = P[(size_t)n * F_TOT + 768 + t + 64];
  __syncthreads();
  int h = t >> 5, k = t & 31;
  const float* km = Km + h * 2048 + k * 64;
  const float* qs = Qs + h * 64;
  float acc = 0.f;
  for (int z = 0; z < 64; z++) acc += qs[z] * km[z];
  float sm = acc * 0.125f;
  float mx = sm;
#pragma unroll
  for (int o = 16; o > 0; o >>= 1) mx = fmaxf(mx, __shfl_xor(mx, o, 64));
  float ex = expf(sm - mx);
  float se = ex;
#pragma unroll
  for (int o = 16; o > 0; o >>= 1) se += __shfl_xor(se, o, 64);
  pmem[t] = ex / se;
  if (k == 0) em[h] = -(mx + logf(se));
  __syncthreads();
#pragma unroll
  for (int pass = 0; pass < 2; pass++){
    int idx = pass * 64 + t;
    int h2 = idx >> 6, z = idx & 63;
    const float* km2 = Km + h2 * 2048;
    const float* ph = pmem + h2 * 32;
    float a = 0.f;
    for (int kk = 0; kk < 32; kk++) a += ph[kk] * km2[kk * 64 + z];
    dP[(size_t)n * F_TOT + 768 + idx] = -0.125f * a; // dQm
  }
  if (t == 0) e_node[n] += em[0] + em[1];
}

// ---------------- node energy + per-graph sum ----------------
__global__ __launch_bounds__(256) void k_node_energy(const unsigned* m2u, const float* z2,
                              const unsigned* m3u, const float* z3,
                              const float* e_node, const int* batch, float* Eg){
  __shared__ float eg[NG_G];
  int t = threadIdx.x;
  if (t < NG_G) eg[t] = 0.f;
  __syncthreads();
  int n = blockIdx.x * 256 + t;
  float e = e_node[n];
#pragma unroll
  for (int h = 0; h < 2; h++){
    float zz = z2[n * 2 + h];
    if (zz > 0.f) e -= (key2f(m2u[n * 2 + h]) + logf(zz));          // lam2 = 1
    float zz3 = z3[n * 2 + h];
    if (zz3 > 0.f) e -= 0.5f * (key2f(m3u[n * 2 + h]) + logf(zz3)); // lam3 = 0.5
  }
  atomicAdd(&eg[batch[n]], e);
  __syncthreads();
  if (t < NG_G) atomicAdd(&Eg[t], eg[t]);
}

// ---------------- edges backward ----------------
__global__ __launch_bounds__(256) void k_edge_bwd(const float* P, const int* c2, const int* u2,
                    const float* s2, const unsigned* m2u, const float* z2, float* dP){
  int e = blockIdx.x * 4 + (threadIdx.x >> 6);
  int z = threadIdx.x & 63;
  int c = c2[e], u = u2[e];
  const float* pc = P + (size_t)c * F_TOT;
  const float* pu = P + (size_t)u * F_TOT + 128;
  float* dc = dP + (size_t)c * F_TOT;
  float* du = dP + (size_t)u * F_TOT + 128;
#pragma unroll
  for (int h = 0; h < 2; h++){
    float m = key2f(m2u[c * 2 + h]);
    float p = expf(s2[(size_t)e * 2 + h] - m) / z2[c * 2 + h];
    float coef = -0.125f * p; // -lam2 * p / sqrt(HD)
    atomicAdd(&dc[h * 64 + z], coef * pu[h * 64 + z]);
    atomicAdd(&du[h * 64 + z], coef * pc[h * 64 + z]);
  }
}

// ---------------- motifs backward ----------------
__global__ __launch_bounds__(256) void k_motif_bwd(const float* P, const int* c3, const int* u3, const int* v3,
                     const int* tt, const float* Ttau, const float* s3, const unsigned* m3u, const float* z3,
                     const float* qkb, const float* tvb, float* dP){
  int m = blockIdx.x * 4 + (threadIdx.x >> 6);
  int z = threadIdx.x & 63;
  int c = c3[m], u = u3[m], v = v3[m], t = tt[m];
  const float* pq  = P + (size_t)c * F_TOT + 256;
  const float* pku = P + (size_t)u * F_TOT + 512;
  float* dq  = dP + (size_t)c * F_TOT + 256;
  float* dku = dP + (size_t)u * F_TOT + 512;
  float* dkv = dP + (size_t)v * F_TOT + 512;
  const float* tb = Ttau + (size_t)t * 256;
#pragma unroll
  for (int h = 0; h < 2; h++){
    float mm = key2f(m3u[c * 2 + h]);
    float p = expf(s3[(size_t)m * 2 + h] - mm) / z3[c * 2 + h];
    float base = -0.5f * p * (1.0f / 64.0f); // -lam3 * p / HD
#pragma unroll
    for (int r = 0; r < 2; r++){
      int o = h * 128 + r * 64 + z;
      float cq = base * tvb[((size_t)m * 2 + h) * 2 + r];
      float ck = base * qkb[((size_t)m * 2 + h) * 2 + r];
      atomicAdd(&dq[o],  cq * pku[o]);
      atomicAdd(&dku[o], cq * pq[o]);
      atomicAdd(&dkv[o], ck * tb[(h * 2 + r) * 64 + z]);
    }
  }
}

// ---------------- backward projection GEMM: dG[n,d] = sum_f dP[n,f]*Wcat[f,d] ----------------
__global__ __launch_bounds__(256) void k_bwd_gemm(const float* dP, const float* Wcat, float* dG){
  __shared__ float dPs[8 * F_TOT];
  int n0 = blockIdx.x * 8, t = threadIdx.x;
  for (int idx = t; idx < 8 * F_TOT; idx += 256) dPs[idx] = dP[(size_t)n0 * F_TOT + idx];
  __syncthreads();
  int d = t & 127, half = t >> 7;
  float acc[4] = {0,0,0,0};
  for (int f = 0; f < F_TOT; f++){
    float w = Wcat[f * 128 + d];
#pragma unroll
    for (int i = 0; i < 4; i++) acc[i] += dPs[(half * 4 + i) * F_TOT + f] * w;
  }
#pragma unroll
  for (int i = 0; i < 4; i++) dG[(size_t)(n0 + half * 4 + i) * 128 + d] = acc[i];
}

// ---------------- finalize: LN backward + clip + step + state clip ----------------
__global__ __launch_bounds__(128) void k_finalize(const float* X, const float* dG, const float* gamma,
                    const float* mu, const float* rstd, const float* step_p, float* out){
  __shared__ float scr[2];
  int n = blockIdx.x, t = threadIdx.x;
  float x = X[(size_t)n * 128 + t];
  float dg = dG[(size_t)n * 128 + t];
  float gam = gamma[t];
  float rs = rstd[n];
  float xhat = (x - mu[n]) * rs;
  float dxh = dg * gam;
  float s1 = bsum128(dxh, scr, t);
  float s2v = bsum128(dxh * xhat, scr, t);
  float dx = rs * (dxh - s1 * (1.0f / 128) - xhat * (s2v * (1.0f / 128)));
  float g = x + dx; // + d(0.5||X||^2)
  float gn = sqrtf(bsum128(g * g, scr, t));
  g *= 1.0f / fmaxf(gn, 1.0f);                 // GRAD_CLIP = 1
  float step = step_p[0];
  float xn = x - step * g;                     // DAMPING = 1
  float sn = sqrtf(bsum128(xn * xn, scr, t));
  xn *= 10.0f / fmaxf(sn, 10.0f);              // STATE_CLIP = 10
  out[(size_t)n * 128 + t] = xn;
}

__global__ void k_write_eg(const float* Eg, float* out){
  int t = threadIdx.x;
  if (t < NG_G) out[(size_t)N_NODES * 128 + t] = Eg[t];
}

extern "C" void kernel_launch(void* const* d_in, const int* in_sizes, int n_in,
                              void* d_out, int out_size, void* d_ws, size_t ws_size,
                              hipStream_t stream) {
  const float* X     = (const float*)d_in[0];
  const int*  c_2    = (const int*) d_in[1];
  const int*  u_2    = (const int*) d_in[2];
  const int*  c_3    = (const int*) d_in[3];
  const int*  u_3    = (const int*) d_in[4];
  const int*  v_3    = (const int*) d_in[5];
  const int*  t_tau  = (const int*) d_in[6];
  const int*  batch  = (const int*) d_in[7];
  const float* a_2   = (const float*)d_in[8];
  const float* step_s= (const float*)d_in[9];
  const float* ln_g  = (const float*)d_in[10];
  const float* ln_b  = (const float*)d_in[11];
  const float* W_Q2  = (const float*)d_in[12];
  const float* W_K2  = (const float*)d_in[13];
  const float* W_Q3  = (const float*)d_in[14];
  const float* W_K3  = (const float*)d_in[15];
  const float* T_tau = (const float*)d_in[16];
  const float* W_Qm  = (const float*)d_in[17];
  const float* W_Km  = (const float*)d_in[18];
  const float* B_mem = (const float*)d_in[19];
  float* out = (float*)d_out;

  float* w = (float*)d_ws;
  float* G      = w; w += (size_t)N_NODES * D_DIM;
  float* P      = w; w += (size_t)N_NODES * F_TOT;
  float* dP     = w; w += (size_t)N_NODES * F_TOT;
  float* Wcat   = w; w += F_TOT * D_DIM;
  float* WcatT  = w; w += F_TOT * D_DIM;
  float* Km     = w; w += 4096;
  float* mu     = w; w += N_NODES;
  float* rstd   = w; w += N_NODES;
  float* s2     = w; w += (size_t)E_EDG * 2;
  unsigned* m2u = (unsigned*)w; w += N_NODES * 2;
  float* z2     = w; w += N_NODES * 2;
  float* s3     = w; w += (size_t)M_MOT * 2;
  float* qkb    = w; w += (size_t)M_MOT * 4;
  float* tvb    = w; w += (size_t)M_MOT * 4;
  unsigned* m3u = (unsigned*)w; w += N_NODES * 2;
  float* z3     = w; w += N_NODES * 2;
  float* e_node = w; w += N_NODES;
  float* Eg     = w; w += NG_G;

  hipMemsetAsync(dP, 0, (size_t)N_NODES * F_TOT * sizeof(float), stream);
  hipLaunchKernelGGL(k_init, dim3(256), dim3(256), 0, stream, m2u, z2, m3u, z3, Eg);
  hipLaunchKernelGGL(k_prep_wcat, dim3((F_TOT * D_DIM + 255) / 256), dim3(256), 0, stream,
                     W_Q2, W_K2, W_Q3, W_K3, W_Qm, Wcat, WcatT);
  hipLaunchKernelGGL(k_prep_km, dim3(16), dim3(256), 0, stream, W_Km, B_mem, Km);
  hipLaunchKernelGGL(k_layernorm, dim3(N_NODES), dim3(128), 0, stream, X, ln_g, ln_b, G, mu, rstd, e_node);
  hipLaunchKernelGGL(k_fwd_gemm, dim3(N_NODES / 8), dim3(256), 0, stream, G, WcatT, P);
  hipLaunchKernelGGL(k_edge_fwd, dim3(E_EDG / 4), dim3(256), 0, stream, P, c_2, u_2, a_2, s2, m2u);
  hipLaunchKernelGGL(k_motif_fwd, dim3(M_MOT / 4), dim3(256), 0, stream, P, c_3, u_3, v_3, t_tau, T_tau, s3, qkb, tvb, m3u);
  hipLaunchKernelGGL(k_edge_z, dim3((E_EDG * 2 + 255) / 256), dim3(256), 0, stream, s2, c_2, m2u, z2);
  hipLaunchKernelGGL(k_motif_z, dim3((M_MOT * 2 + 255) / 256), dim3(256), 0, stream, s3, c_3, m3u, z3);
  hipLaunchKernelGGL(k_mem, dim3(N_NODES), dim3(64), 0, stream, P, Km, dP, e_node);
  hipLaunchKernelGGL(k_node_energy, dim3(N_NODES / 256), dim3(256), 0, stream, m2u, z2, m3u, z3, e_node, batch, Eg);
  hipLaunchKernelGGL(k_edge_bwd, dim3(E_EDG / 4), dim3(256), 0, stream, P, c_2, u_2, s2, m2u, z2, dP);
  hipLaunchKernelGGL(k_motif_bwd, dim3(M_MOT / 4), dim3(256), 0, stream, P, c_3, u_3, v_3, t_tau, T_tau, s3, m3u, z3, qkb, tvb, dP);
  hipLaunchKernelGGL(k_bwd_gemm, dim3(N_NODES / 8), dim3(256), 0, stream, dP, Wcat, G /*reuse G as dG*/);
  hipLaunchKernelGGL(k_finalize, dim3(N_NODES), dim3(128), 0, stream, X, G, ln_g, mu, rstd, step_s, out);
  hipLaunchKernelGGL(k_write_eg, dim3(1), dim3(64), 0, stream, Eg, out);
}

// Round 3
// 943.565 us; speedup vs baseline: 1.3850x; 1.3850x over previous
//
#include <hip/hip_runtime.h>
#include <hip/hip_bf16.h>
#include <math.h>

typedef __hip_bfloat16 bf16;

#define N_NODES 32768
#define D_DIM 128
#define E_EDG 262144
#define M_MOT 131072
#define NG_G 32
#define F_TOT 896
// P slices: Q2 [0,128) K2 [128,256) Q3 [256,512) K3 [512,768) Qm [768,896)
// constants: lam2=1, lam3=0.5, lamm=1, b2=b3=bm=1 (softplus of stored raws)

__device__ __forceinline__ float wsum64(float v){
#pragma unroll
  for (int o = 32; o > 0; o >>= 1) v += __shfl_xor(v, o, 64);
  return v;
}

__device__ __forceinline__ float bsum128(float v, float* scr, int t){
  float s = wsum64(v);
  if ((t & 63) == 0) scr[t >> 6] = s;
  __syncthreads();
  float r = scr[0] + scr[1];
  __syncthreads();
  return r;
}

// ---------------- prep ----------------
__global__ void k_prep_wcat(const float* wq2, const float* wk2, const float* wq3,
                            const float* wk3, const float* wqm,
                            float* Wcat, float* WcatT){
  int idx = blockIdx.x * 256 + threadIdx.x;
  if (idx >= F_TOT * D_DIM) return;
  int f = idx / D_DIM, d = idx - f * D_DIM;
  const float* src; int fr;
  if      (f < 128){ src = wq2; fr = f; }
  else if (f < 256){ src = wk2; fr = f - 128; }
  else if (f < 512){ src = wq3; fr = f - 256; }
  else if (f < 768){ src = wk3; fr = f - 512; }
  else             { src = wqm; fr = f - 768; }
  float v = src[fr * D_DIM + d];
  Wcat[f * D_DIM + d] = v;
  WcatT[d * F_TOT + f] = v;
}

__global__ void k_prep_km(const float* wkm, const float* bmem, float* Km){
  int idx = blockIdx.x * 256 + threadIdx.x; // H*K*HD = 4096
  if (idx >= 4096) return;
  int z = idx & 63, k = (idx >> 6) & 31, h = idx >> 11;
  const float* wrow = wkm + (h * 64 + z) * D_DIM;
  const float* brow = bmem + k * D_DIM;
  float acc = 0.f;
  for (int d = 0; d < D_DIM; d++) acc += wrow[d] * brow[d];
  Km[idx] = acc; // layout [h][k][z]
}

__global__ void k_zero(int* cntcur, float* Eg){
  int idx = blockIdx.x * 256 + threadIdx.x;
  if (idx < 5 * N_NODES) cntcur[idx] = 0;
  if (idx < NG_G) Eg[idx] = 0.f;
}

// ---------------- CSR build ----------------
__global__ void k_hist(const int* c2, const int* u2, const int* c3, const int* u3,
                       const int* v3, int* cnt){
  int i = blockIdx.x * 256 + threadIdx.x;
  if (i < E_EDG){
    atomicAdd(&cnt[c2[i]], 1);
    atomicAdd(&cnt[N_NODES + u2[i]], 1);
  }
  if (i < M_MOT){
    atomicAdd(&cnt[2 * N_NODES + c3[i]], 1);
    atomicAdd(&cnt[3 * N_NODES + u3[i]], 1);
    atomicAdd(&cnt[4 * N_NODES + v3[i]], 1);
  }
}

__global__ __launch_bounds__(1024) void k_scan(int* cntcur, int* off){
  __shared__ int sd[1024];
  int a = blockIdx.x;                 // which of the 5 lists
  int* c = cntcur + a * N_NODES;      // counts in, cursors out (in place)
  int* o = off + a * (N_NODES + 1);
  int t = threadIdx.x;
  int loc[32];
  int sum = 0;
#pragma unroll
  for (int j = 0; j < 32; j++){ loc[j] = sum; sum += c[t * 32 + j]; }
  sd[t] = sum;
  __syncthreads();
  for (int s = 1; s < 1024; s <<= 1){
    int v = (t >= s) ? sd[t - s] : 0;
    __syncthreads();
    sd[t] += v;
    __syncthreads();
  }
  int excl = sd[t] - sum;
#pragma unroll
  for (int j = 0; j < 32; j++){
    int val = excl + loc[j];
    o[t * 32 + j] = val;
    c[t * 32 + j] = val;   // cursor = start offset
  }
  if (t == 1023) o[N_NODES] = sd[1023];
}

__global__ void k_fill(const int* c2, const int* u2, const int* c3, const int* u3,
                       const int* v3, int* cur,
                       int* lec, int* leu, int* lmc, int* lmu, int* lmv){
  int i = blockIdx.x * 256 + threadIdx.x;
  if (i < E_EDG){
    lec[atomicAdd(&cur[c2[i]], 1)] = i;
    leu[atomicAdd(&cur[N_NODES + u2[i]], 1)] = i;
  }
  if (i < M_MOT){
    lmc[atomicAdd(&cur[2 * N_NODES + c3[i]], 1)] = i;
    lmu[atomicAdd(&cur[3 * N_NODES + u3[i]], 1)] = i;
    lmv[atomicAdd(&cur[4 * N_NODES + v3[i]], 1)] = i;
  }
}

// ---------------- layernorm forward ----------------
__global__ __launch_bounds__(128) void k_layernorm(const float* X, const float* gamma, const float* beta,
                            float* G, float* mu, float* rstd, float* e_node){
  __shared__ float scr[2];
  int n = blockIdx.x, t = threadIdx.x;
  float x = X[(size_t)n * D_DIM + t];
  float sumx = bsum128(x, scr, t);
  float m = sumx * (1.0f / D_DIM);
  float xm = x - m;
  float var = bsum128(xm * xm, scr, t) * (1.0f / D_DIM);
  float rs = rsqrtf(var + 1e-5f);
  G[(size_t)n * D_DIM + t] = gamma[t] * xm * rs + beta[t];
  float sxx = bsum128(x * x, scr, t);
  if (t == 0){ mu[n] = m; rstd[n] = rs; e_node[n] = 0.5f * sxx; }
}

// ---------------- forward projection GEMM: P[n,f] = sum_d G[n,d]*Wcat[f,d] (bf16 out) ----
__global__ __launch_bounds__(256) void k_fwd_gemm(const float* G, const float* WcatT, bf16* P){
  __shared__ float Gs[8 * 128];
  int n0 = blockIdx.x * 8, t = threadIdx.x;
  for (int idx = t; idx < 8 * 128; idx += 256) Gs[idx] = G[(size_t)n0 * 128 + idx];
  __syncthreads();
  for (int fo = 0; fo < F_TOT; fo += 256){
    int f = fo + t;
    if (f < F_TOT){
      float acc[8] = {0,0,0,0,0,0,0,0};
      for (int d = 0; d < 128; d++){
        float w = WcatT[d * F_TOT + f];
#pragma unroll
        for (int i = 0; i < 8; i++) acc[i] += Gs[i * 128 + d] * w;
      }
#pragma unroll
      for (int i = 0; i < 8; i++) P[(size_t)(n0 + i) * F_TOT + f] = __float2bfloat16(acc[i]);
    }
  }
}

// ---------------- edges: per-target-node online softmax + dQ2 ----------------
__global__ __launch_bounds__(256) void k_edge_c(const bf16* P, const int* u2, const float* a2,
                  const int* off, const int* lst, float* s2,
                  float* m2, float* z2, bf16* dP, float* e_node){
  int n = blockIdx.x * 4 + (threadIdx.x >> 6);
  int z = threadIdx.x & 63;
  int beg = off[n], end = off[n + 1];
  const bf16* pq = P + (size_t)n * F_TOT;
  float q0 = __bfloat162float(pq[z]);
  float q1 = __bfloat162float(pq[64 + z]);
  float m0 = -INFINITY, m1 = -INFINITY, z0 = 0.f, z1 = 0.f;
  float acc0 = 0.f, acc1 = 0.f;
  for (int i = beg; i < end; i++){
    int e = lst[i];
    int u = u2[e];
    const bf16* pk = P + (size_t)u * F_TOT + 128;
    float k0 = __bfloat162float(pk[z]);
    float k1 = __bfloat162float(pk[64 + z]);
    float s0 = wsum64(q0 * k0) * 0.125f + a2[(size_t)e * 2 + 0];
    float s1 = wsum64(q1 * k1) * 0.125f + a2[(size_t)e * 2 + 1];
    if (z == 0){ s2[(size_t)e * 2 + 0] = s0; s2[(size_t)e * 2 + 1] = s1; }
    float mn0 = fmaxf(m0, s0), sc0 = expf(m0 - mn0), ex0 = expf(s0 - mn0);
    acc0 = acc0 * sc0 + ex0 * k0;  z0 = z0 * sc0 + ex0;  m0 = mn0;
    float mn1 = fmaxf(m1, s1), sc1 = expf(m1 - mn1), ex1 = expf(s1 - mn1);
    acc1 = acc1 * sc1 + ex1 * k1;  z1 = z1 * sc1 + ex1;  m1 = mn1;
  }
  bf16* dq = dP + (size_t)n * F_TOT;
  dq[z]      = __float2bfloat16((z0 > 0.f) ? -0.125f * acc0 / z0 : 0.f);
  dq[64 + z] = __float2bfloat16((z1 > 0.f) ? -0.125f * acc1 / z1 : 0.f);
  if (z == 0){
    float e = 0.f;
    if (z0 > 0.f) e -= (m0 + logf(z0));
    if (z1 > 0.f) e -= (m1 + logf(z1));
    e_node[n] += e;                 // lam2 = 1
    m2[n * 2] = m0; z2[n * 2] = z0; m2[n * 2 + 1] = m1; z2[n * 2 + 1] = z1;
  }
}

// scores -> probabilities in place
__global__ void k_p2(float* s2, const int* c2, const float* m2, const float* z2){
  int idx = blockIdx.x * 256 + threadIdx.x;
  if (idx >= E_EDG * 2) return;
  int e = idx >> 1, h = idx & 1;
  int c = c2[e];
  float zz = z2[c * 2 + h];
  s2[idx] = (zz > 0.f) ? expf(s2[idx] - m2[c * 2 + h]) / zz : 0.f;
}

// dK2[u] = -0.125 * sum p * Q2[c]
__global__ __launch_bounds__(256) void k_edge_u(const bf16* P, const int* c2, const float* p2,
                  const int* off, const int* lst, bf16* dP){
  int n = blockIdx.x * 4 + (threadIdx.x >> 6);
  int z = threadIdx.x & 63;
  int beg = off[n], end = off[n + 1];
  float acc0 = 0.f, acc1 = 0.f;
  for (int i = beg; i < end; i++){
    int e = lst[i];
    int c = c2[e];
    const bf16* pq = P + (size_t)c * F_TOT;
    acc0 += p2[(size_t)e * 2 + 0] * __bfloat162float(pq[z]);
    acc1 += p2[(size_t)e * 2 + 1] * __bfloat162float(pq[64 + z]);
  }
  bf16* dk = dP + (size_t)n * F_TOT + 128;
  dk[z]      = __float2bfloat16(-0.125f * acc0);
  dk[64 + z] = __float2bfloat16(-0.125f * acc1);
}

// ---------------- motifs: per-c online softmax + dQ3 ----------------
__global__ __launch_bounds__(256) void k_motif_c(const bf16* P, const int* u3, const int* v3,
                   const int* tt, const float* Ttau, const int* off, const int* lst,
                   float* s3, float* qkb, float* tvb, float* m3, float* z3,
                   bf16* dP, float* e_node){
  int n = blockIdx.x * 4 + (threadIdx.x >> 6);
  int z = threadIdx.x & 63;
  int beg = off[n], end = off[n + 1];
  const bf16* pq = P + (size_t)n * F_TOT + 256;
  float q[4];
#pragma unroll
  for (int hr = 0; hr < 4; hr++) q[hr] = __bfloat162float(pq[hr * 64 + z]);
  float m0 = -INFINITY, m1 = -INFINITY, z0 = 0.f, z1 = 0.f;
  float acc[4] = {0.f, 0.f, 0.f, 0.f};
  for (int i = beg; i < end; i++){
    int m = lst[i];
    int u = u3[m], v = v3[m], t = tt[m];
    const bf16* pu = P + (size_t)u * F_TOT + 512;
    const bf16* pv = P + (size_t)v * F_TOT + 512;
    const float* pt = Ttau + (size_t)t * 256;
    float ku[4], qk[4], tv[4];
#pragma unroll
    for (int hr = 0; hr < 4; hr++){
      ku[hr] = __bfloat162float(pu[hr * 64 + z]);
      float kv = __bfloat162float(pv[hr * 64 + z]);
      qk[hr] = wsum64(q[hr] * ku[hr]);
      tv[hr] = wsum64(pt[hr * 64 + z] * kv);
    }
    float s0 = (qk[0] * tv[0] + qk[1] * tv[1]) * (1.0f / 64.0f);
    float s1 = (qk[2] * tv[2] + qk[3] * tv[3]) * (1.0f / 64.0f);
    if (z == 0){
      s3[(size_t)m * 2 + 0] = s0; s3[(size_t)m * 2 + 1] = s1;
#pragma unroll
      for (int hr = 0; hr < 4; hr++){ qkb[(size_t)m * 4 + hr] = qk[hr]; tvb[(size_t)m * 4 + hr] = tv[hr]; }
    }
    float mn0 = fmaxf(m0, s0), sc0 = expf(m0 - mn0), ex0 = expf(s0 - mn0);
    acc[0] = acc[0] * sc0 + ex0 * tv[0] * ku[0];
    acc[1] = acc[1] * sc0 + ex0 * tv[1] * ku[1];
    z0 = z0 * sc0 + ex0;  m0 = mn0;
    float mn1 = fmaxf(m1, s1), sc1 = expf(m1 - mn1), ex1 = expf(s1 - mn1);
    acc[2] = acc[2] * sc1 + ex1 * tv[2] * ku[2];
    acc[3] = acc[3] * sc1 + ex1 * tv[3] * ku[3];
    z1 = z1 * sc1 + ex1;  m1 = mn1;
  }
  bf16* dq = dP + (size_t)n * F_TOT + 256;
  const float cst = -0.5f / 64.0f;
  dq[z]       = __float2bfloat16((z0 > 0.f) ? cst * acc[0] / z0 : 0.f);
  dq[64 + z]  = __float2bfloat16((z0 > 0.f) ? cst * acc[1] / z0 : 0.f);
  dq[128 + z] = __float2bfloat16((z1 > 0.f) ? cst * acc[2] / z1 : 0.f);
  dq[192 + z] = __float2bfloat16((z1 > 0.f) ? cst * acc[3] / z1 : 0.f);
  if (z == 0){
    float e = 0.f;
    if (z0 > 0.f) e -= 0.5f * (m0 + logf(z0));   // lam3 = 0.5
    if (z1 > 0.f) e -= 0.5f * (m1 + logf(z1));
    e_node[n] += e;
    m3[n * 2] = m0; z3[n * 2] = z0; m3[n * 2 + 1] = m1; z3[n * 2 + 1] = z1;
  }
}

__global__ void k_p3(float* s3, const int* c3, const float* m3, const float* z3){
  int idx = blockIdx.x * 256 + threadIdx.x;
  if (idx >= M_MOT * 2) return;
  int m = idx >> 1, h = idx & 1;
  int c = c3[m];
  float zz = z3[c * 2 + h];
  s3[idx] = (zz > 0.f) ? expf(s3[idx] - m3[c * 2 + h]) / zz : 0.f;
}

// dK3[n] from u-role and v-role contributions
__global__ __launch_bounds__(256) void k_motif_uv(const bf16* P, const int* c3, const int* tt,
                    const float* Ttau, const float* p3, const float* qkb, const float* tvb,
                    const int* offu, const int* lstu, const int* offv, const int* lstv, bf16* dP){
  int n = blockIdx.x * 4 + (threadIdx.x >> 6);
  int z = threadIdx.x & 63;
  float acc[4] = {0.f, 0.f, 0.f, 0.f};
  int beg = offu[n], end = offu[n + 1];
  for (int i = beg; i < end; i++){
    int m = lstu[i];
    int c = c3[m];
    const bf16* pq = P + (size_t)c * F_TOT + 256;
    float p0 = p3[(size_t)m * 2 + 0], p1 = p3[(size_t)m * 2 + 1];
    acc[0] += p0 * tvb[(size_t)m * 4 + 0] * __bfloat162float(pq[z]);
    acc[1] += p0 * tvb[(size_t)m * 4 + 1] * __bfloat162float(pq[64 + z]);
    acc[2] += p1 * tvb[(size_t)m * 4 + 2] * __bfloat162float(pq[128 + z]);
    acc[3] += p1 * tvb[(size_t)m * 4 + 3] * __bfloat162float(pq[192 + z]);
  }
  beg = offv[n]; end = offv[n + 1];
  for (int i = beg; i < end; i++){
    int m = lstv[i];
    int t = tt[m];
    const float* pt = Ttau + (size_t)t * 256;
    float p0 = p3[(size_t)m * 2 + 0], p1 = p3[(size_t)m * 2 + 1];
    acc[0] += p0 * qkb[(size_t)m * 4 + 0] * pt[z];
    acc[1] += p0 * qkb[(size_t)m * 4 + 1] * pt[64 + z];
    acc[2] += p1 * qkb[(size_t)m * 4 + 2] * pt[128 + z];
    acc[3] += p1 * qkb[(size_t)m * 4 + 3] * pt[192 + z];
  }
  bf16* dk = dP + (size_t)n * F_TOT + 512;
  const float cst = -0.5f / 64.0f;
#pragma unroll
  for (int hr = 0; hr < 4; hr++) dk[hr * 64 + z] = __float2bfloat16(cst * acc[hr]);
}

// ---------------- memory term: forward + backward fused (node-local) ----------------
__global__ __launch_bounds__(64) void k_mem(const bf16* P, const float* Km, bf16* dP, float* e_node){
  __shared__ float Qs[128];
  __shared__ float pmem[64];
  __shared__ float em[2];
  int n = blockIdx.x, t = threadIdx.x;
  Qs[t]      = __bfloat162float(P[(size_t)n * F_TOT + 768 + t]);
  Qs[t + 64] = __bfloat162float(P[(size_t)n * F_TOT + 768 + t + 64]);
  __syncthreads();
  int h = t >> 5, k = t & 31;
  const float* km = Km + h * 2048 + k * 64;
  const float* qs = Qs + h * 64;
  float acc = 0.f;
  for (int z = 0; z < 64; z++) acc += qs[z] * km[z];
  float sm = acc * 0.125f;
  float mx = sm;
#pragma unroll
  for (int o = 16; o > 0; o >>= 1) mx = fmaxf(mx, __shfl_xor(mx, o, 64));
  float ex = expf(sm - mx);
  float se = ex;
#pragma unroll
  for (int o = 16; o > 0; o >>= 1) se += __shfl_xor(se, o, 64);
  pmem[t] = ex / se;
  if (k == 0) em[h] = -(mx + logf(se));
  __syncthreads();
#pragma unroll
  for (int pass = 0; pass < 2; pass++){
    int idx = pass * 64 + t;
    int h2 = idx >> 6, z = idx & 63;
    const float* km2 = Km + h2 * 2048;
    const float* ph = pmem + h2 * 32;
    float a = 0.f;
    for (int kk = 0; kk < 32; kk++) a += ph[kk] * km2[kk * 64 + z];
    dP[(size_t)n * F_TOT + 768 + idx] = __float2bfloat16(-0.125f * a);
  }
  if (t == 0) e_node[n] += em[0] + em[1];
}

// ---------------- per-graph energy sum ----------------
__global__ __launch_bounds__(256) void k_node_energy(const float* e_node, const int* batch, float* Eg){
  __shared__ float eg[NG_G];
  int t = threadIdx.x;
  if (t < NG_G) eg[t] = 0.f;
  __syncthreads();
  int n = blockIdx.x * 256 + t;
  atomicAdd(&eg[batch[n]], e_node[n]);
  __syncthreads();
  if (t < NG_G) atomicAdd(&Eg[t], eg[t]);
}

// ---------------- backward projection GEMM: dG[n,d] = sum_f dP[n,f]*Wcat[f,d] ----------------
__global__ __launch_bounds__(256) void k_bwd_gemm(const bf16* dP, const float* Wcat, float* dG){
  __shared__ float dPs[8 * F_TOT];
  int n0 = blockIdx.x * 8, t = threadIdx.x;
  for (int idx = t; idx < 8 * F_TOT; idx += 256)
    dPs[idx] = __bfloat162float(dP[(size_t)n0 * F_TOT + idx]);
  __syncthreads();
  int d = t & 127, half = t >> 7;
  float acc[4] = {0,0,0,0};
  for (int f = 0; f < F_TOT; f++){
    float w = Wcat[f * 128 + d];
#pragma unroll
    for (int i = 0; i < 4; i++) acc[i] += dPs[(half * 4 + i) * F_TOT + f] * w;
  }
#pragma unroll
  for (int i = 0; i < 4; i++) dG[(size_t)(n0 + half * 4 + i) * 128 + d] = acc[i];
}

// ---------------- finalize: LN backward + clip + step + state clip ----------------
__global__ __launch_bounds__(128) void k_finalize(const float* X, const float* dG, const float* gamma,
                    const float* mu, const float* rstd, const float* step_p, float* out){
  __shared__ float scr[2];
  int n = blockIdx.x, t = threadIdx.x;
  float x = X[(size_t)n * 128 + t];
  float dg = dG[(size_t)n * 128 + t];
  float gam = gamma[t];
  float rs = rstd[n];
  float xhat = (x - mu[n]) * rs;
  float dxh = dg * gam;
  float s1 = bsum128(dxh, scr, t);
  float s2v = bsum128(dxh * xhat, scr, t);
  float dx = rs * (dxh - s1 * (1.0f / 128) - xhat * (s2v * (1.0f / 128)));
  float g = x + dx;
  float gn = sqrtf(bsum128(g * g, scr, t));
  g *= 1.0f / fmaxf(gn, 1.0f);
  float step = step_p[0];
  float xn = x - step * g;
  float sn = sqrtf(bsum128(xn * xn, scr, t));
  xn *= 10.0f / fmaxf(sn, 10.0f);
  out[(size_t)n * 128 + t] = xn;
}

__global__ void k_write_eg(const float* Eg, float* out){
  int t = threadIdx.x;
  if (t < NG_G) out[(size_t)N_NODES * 128 + t] = Eg[t];
}

extern "C" void kernel_launch(void* const* d_in, const int* in_sizes, int n_in,
                              void* d_out, int out_size, void* d_ws, size_t ws_size,
                              hipStream_t stream) {
  const float* X     = (const float*)d_in[0];
  const int*  c_2    = (const int*) d_in[1];
  const int*  u_2    = (const int*) d_in[2];
  const int*  c_3    = (const int*) d_in[3];
  const int*  u_3    = (const int*) d_in[4];
  const int*  v_3    = (const int*) d_in[5];
  const int*  t_tau  = (const int*) d_in[6];
  const int*  batch  = (const int*) d_in[7];
  const float* a_2   = (const float*)d_in[8];
  const float* step_s= (const float*)d_in[9];
  const float* ln_g  = (const float*)d_in[10];
  const float* ln_b  = (const float*)d_in[11];
  const float* W_Q2  = (const float*)d_in[12];
  const float* W_K2  = (const float*)d_in[13];
  const float* W_Q3  = (const float*)d_in[14];
  const float* W_K3  = (const float*)d_in[15];
  const float* T_tau = (const float*)d_in[16];
  const float* W_Qm  = (const float*)d_in[17];
  const float* W_Km  = (const float*)d_in[18];
  const float* B_mem = (const float*)d_in[19];
  float* out = (float*)d_out;

  char* wb = (char*)d_ws;
  float* G      = (float*)wb; wb += (size_t)N_NODES * D_DIM * 4;
  float* Wcat   = (float*)wb; wb += F_TOT * D_DIM * 4;
  float* WcatT  = (float*)wb; wb += F_TOT * D_DIM * 4;
  float* Km     = (float*)wb; wb += 4096 * 4;
  float* mu     = (float*)wb; wb += N_NODES * 4;
  float* rstd   = (float*)wb; wb += N_NODES * 4;
  float* s2     = (float*)wb; wb += (size_t)E_EDG * 2 * 4;   // scores -> probs in place
  float* m2     = (float*)wb; wb += N_NODES * 2 * 4;
  float* z2     = (float*)wb; wb += N_NODES * 2 * 4;
  float* s3     = (float*)wb; wb += (size_t)M_MOT * 2 * 4;
  float* qkb    = (float*)wb; wb += (size_t)M_MOT * 4 * 4;
  float* tvb    = (float*)wb; wb += (size_t)M_MOT * 4 * 4;
  float* m3     = (float*)wb; wb += N_NODES * 2 * 4;
  float* z3     = (float*)wb; wb += N_NODES * 2 * 4;
  float* e_node = (float*)wb; wb += N_NODES * 4;
  float* Eg     = (float*)wb; wb += NG_G * 4;
  bf16* P       = (bf16*)wb;  wb += (size_t)N_NODES * F_TOT * 2;
  bf16* dP      = (bf16*)wb;  wb += (size_t)N_NODES * F_TOT * 2;
  int* cntcur   = (int*)wb;   wb += 5 * N_NODES * 4;
  int* off      = (int*)wb;   wb += 5 * (N_NODES + 1) * 4;
  int* lec      = (int*)wb;   wb += E_EDG * 4;
  int* leu      = (int*)wb;   wb += E_EDG * 4;
  int* lmc      = (int*)wb;   wb += M_MOT * 4;
  int* lmu      = (int*)wb;   wb += M_MOT * 4;
  int* lmv      = (int*)wb;   wb += M_MOT * 4;

  const int* off_ec = off;
  const int* off_eu = off + (N_NODES + 1);
  const int* off_mc = off + 2 * (N_NODES + 1);
  const int* off_mu = off + 3 * (N_NODES + 1);
  const int* off_mv = off + 4 * (N_NODES + 1);

  hipLaunchKernelGGL(k_zero, dim3((5 * N_NODES + 255) / 256), dim3(256), 0, stream, cntcur, Eg);
  hipLaunchKernelGGL(k_prep_wcat, dim3((F_TOT * D_DIM + 255) / 256), dim3(256), 0, stream,
                     W_Q2, W_K2, W_Q3, W_K3, W_Qm, Wcat, WcatT);
  hipLaunchKernelGGL(k_prep_km, dim3(16), dim3(256), 0, stream, W_Km, B_mem, Km);
  hipLaunchKernelGGL(k_hist, dim3((E_EDG + 255) / 256), dim3(256), 0, stream,
                     c_2, u_2, c_3, u_3, v_3, cntcur);
  hipLaunchKernelGGL(k_scan, dim3(5), dim3(1024), 0, stream, cntcur, off);
  hipLaunchKernelGGL(k_fill, dim3((E_EDG + 255) / 256), dim3(256), 0, stream,
                     c_2, u_2, c_3, u_3, v_3, cntcur, lec, leu, lmc, lmu, lmv);
  hipLaunchKernelGGL(k_layernorm, dim3(N_NODES), dim3(128), 0, stream, X, ln_g, ln_b, G, mu, rstd, e_node);
  hipLaunchKernelGGL(k_fwd_gemm, dim3(N_NODES / 8), dim3(256), 0, stream, G, WcatT, P);
  hipLaunchKernelGGL(k_edge_c, dim3(N_NODES / 4), dim3(256), 0, stream,
                     P, u_2, a_2, off_ec, lec, s2, m2, z2, dP, e_node);
  hipLaunchKernelGGL(k_p2, dim3((E_EDG * 2 + 255) / 256), dim3(256), 0, stream, s2, c_2, m2, z2);
  hipLaunchKernelGGL(k_edge_u, dim3(N_NODES / 4), dim3(256), 0, stream, P, c_2, s2, off_eu, leu, dP);
  hipLaunchKernelGGL(k_motif_c, dim3(N_NODES / 4), dim3(256), 0, stream,
                     P, u_3, v_3, t_tau, T_tau, off_mc, lmc, s3, qkb, tvb, m3, z3, dP, e_node);
  hipLaunchKernelGGL(k_p3, dim3((M_MOT * 2 + 255) / 256), dim3(256), 0, stream, s3, c_3, m3, z3);
  hipLaunchKernelGGL(k_motif_uv, dim3(N_NODES / 4), dim3(256), 0, stream,
                     P, c_3, t_tau, T_tau, s3, qkb, tvb, off_mu, lmu, off_mv, lmv, dP);
  hipLaunchKernelGGL(k_mem, dim3(N_NODES), dim3(64), 0, stream, P, Km, dP, e_node);
  hipLaunchKernelGGL(k_node_energy, dim3(N_NODES / 256), dim3(256), 0, stream, e_node, batch, Eg);
  hipLaunchKernelGGL(k_bwd_gemm, dim3(N_NODES / 8), dim3(256), 0, stream, dP, Wcat, G /*reuse G as dG*/);
  hipLaunchKernelGGL(k_finalize, dim3(N_NODES), dim3(128), 0, stream, X, G, ln_g, mu, rstd, step_s, out);
  hipLaunchKernelGGL(k_write_eg, dim3(1), dim3(64), 0, stream, Eg, out);
}

// Round 4
// 619.979 us; speedup vs baseline: 2.1078x; 1.5219x over previous
//
#include <hip/hip_runtime.h>
#include <hip/hip_bf16.h>
#include <math.h>

typedef __hip_bfloat16 bf16;
typedef short bf16x8 __attribute__((ext_vector_type(8)));
typedef float f32x4 __attribute__((ext_vector_type(4)));

#define N_NODES 32768
#define D_DIM 128
#define E_EDG 262144
#define M_MOT 131072
#define NG_G 32
#define F_TOT 896
// P slices: Q2 [0,128) K2 [128,256) Q3 [256,512) K3 [512,768) Qm [768,896)
// constants: lam2=1, lam3=0.5, lamm=1, b2=b3=bm=1 (softplus of stored raws)

__device__ __forceinline__ float wsum64(float v){
#pragma unroll
  for (int o = 32; o > 0; o >>= 1) v += __shfl_xor(v, o, 64);
  return v;
}
__device__ __forceinline__ float hsum32(float v){   // sums within 32-lane halves
#pragma unroll
  for (int o = 16; o > 0; o >>= 1) v += __shfl_xor(v, o, 64);
  return v;
}
__device__ __forceinline__ float hsum16(float v){   // sums within 16-lane groups
#pragma unroll
  for (int o = 8; o > 0; o >>= 1) v += __shfl_xor(v, o, 64);
  return v;
}
__device__ __forceinline__ float bsum128(float v, float* scr, int t){
  float s = wsum64(v);
  if ((t & 63) == 0) scr[t >> 6] = s;
  __syncthreads();
  float r = scr[0] + scr[1];
  __syncthreads();
  return r;
}
__device__ __forceinline__ float bflo(unsigned u){ return __uint_as_float(u << 16); }
__device__ __forceinline__ float bfhi(unsigned u){ return __uint_as_float(u & 0xffff0000u); }
__device__ __forceinline__ unsigned packbf(float x, float y){
  bf16 a = __float2bfloat16(x), b = __float2bfloat16(y);
  unsigned short ua = *(unsigned short*)&a, ub = *(unsigned short*)&b;
  return (unsigned)ua | ((unsigned)ub << 16);
}

// ---------------- prep ----------------
__global__ void k_prep_wcat(const float* wq2, const float* wk2, const float* wq3,
                            const float* wk3, const float* wqm, float* Wcat){
  int idx = blockIdx.x * 256 + threadIdx.x;
  if (idx >= F_TOT * D_DIM) return;
  int f = idx / D_DIM, d = idx - f * D_DIM;
  const float* src; int fr;
  if      (f < 128){ src = wq2; fr = f; }
  else if (f < 256){ src = wk2; fr = f - 128; }
  else if (f < 512){ src = wq3; fr = f - 256; }
  else if (f < 768){ src = wk3; fr = f - 512; }
  else             { src = wqm; fr = f - 768; }
  Wcat[f * D_DIM + d] = src[fr * D_DIM + d];
}

// pack B-fragments for both GEMMs.
// fwd:  B[k=d][n=f]   -> wfF[((tn*4+kt)*64+lane)*8+j]  = Wcat[tn*16+(lane&15)][kt*32+(lane>>4)*8+j]
// bwd:  B[k=f][n=d]   -> wfB[((td*28+tf)*64+lane)*8+j] = Wcat[tf*32+(lane>>4)*8+j][td*16+(lane&15)]
__global__ void k_pack_frags(const float* Wcat, bf16* wfF, bf16* wfB){
  int idx = blockIdx.x * 256 + threadIdx.x;  // 114688 each
  if (idx >= 114688) return;
  int j = idx & 7, lane = (idx >> 3) & 63, t = idx >> 9; // t in 0..223
  {
    int tn = t >> 2, kt = t & 3;
    int f = tn * 16 + (lane & 15), d = kt * 32 + (lane >> 4) * 8 + j;
    wfF[idx] = __float2bfloat16(Wcat[f * 128 + d]);
  }
  {
    int td = t / 28, tf = t - td * 28;
    int f = tf * 32 + (lane >> 4) * 8 + j, d = td * 16 + (lane & 15);
    wfB[idx] = __float2bfloat16(Wcat[f * 128 + d]);
  }
}

__global__ void k_prep_km(const float* wkm, const float* bmem, float* Km){
  int idx = blockIdx.x * 256 + threadIdx.x; // H*K*HD = 4096
  if (idx >= 4096) return;
  int z = idx & 63, k = (idx >> 6) & 31, h = idx >> 11;
  const float* wrow = wkm + (h * 64 + z) * D_DIM;
  const float* brow = bmem + k * D_DIM;
  float acc = 0.f;
  for (int d = 0; d < D_DIM; d++) acc += wrow[d] * brow[d];
  Km[idx] = acc; // layout [h][k][z]
}

__global__ void k_zero(int* cntcur, float* Eg){
  int idx = blockIdx.x * 256 + threadIdx.x;
  if (idx < 5 * N_NODES) cntcur[idx] = 0;
  if (idx < NG_G) Eg[idx] = 0.f;
}

// ---------------- CSR build ----------------
__global__ void k_hist(const int* c2, const int* u2, const int* c3, const int* u3,
                       const int* v3, int* cnt){
  int i = blockIdx.x * 256 + threadIdx.x;
  if (i < E_EDG){
    atomicAdd(&cnt[c2[i]], 1);
    atomicAdd(&cnt[N_NODES + u2[i]], 1);
  }
  if (i < M_MOT){
    atomicAdd(&cnt[2 * N_NODES + c3[i]], 1);
    atomicAdd(&cnt[3 * N_NODES + u3[i]], 1);
    atomicAdd(&cnt[4 * N_NODES + v3[i]], 1);
  }
}

__global__ __launch_bounds__(1024) void k_scan(int* cntcur, int* off){
  __shared__ int sd[1024];
  int a = blockIdx.x;
  int* c = cntcur + a * N_NODES;
  int* o = off + a * (N_NODES + 1);
  int t = threadIdx.x;
  int loc[32];
  int sum = 0;
#pragma unroll
  for (int j = 0; j < 32; j++){ loc[j] = sum; sum += c[t * 32 + j]; }
  sd[t] = sum;
  __syncthreads();
  for (int s = 1; s < 1024; s <<= 1){
    int v = (t >= s) ? sd[t - s] : 0;
    __syncthreads();
    sd[t] += v;
    __syncthreads();
  }
  int excl = sd[t] - sum;
#pragma unroll
  for (int j = 0; j < 32; j++){
    int val = excl + loc[j];
    o[t * 32 + j] = val;
    c[t * 32 + j] = val;
  }
  if (t == 1023) o[N_NODES] = sd[1023];
}

__global__ void k_fill(const int* c2, const int* u2, const int* c3, const int* u3,
                       const int* v3, int* cur,
                       int* lec, int* leu, int* lmc, int* lmu, int* lmv){
  int i = blockIdx.x * 256 + threadIdx.x;
  if (i < E_EDG){
    lec[atomicAdd(&cur[c2[i]], 1)] = i;
    leu[atomicAdd(&cur[N_NODES + u2[i]], 1)] = i;
  }
  if (i < M_MOT){
    lmc[atomicAdd(&cur[2 * N_NODES + c3[i]], 1)] = i;
    lmu[atomicAdd(&cur[3 * N_NODES + u3[i]], 1)] = i;
    lmv[atomicAdd(&cur[4 * N_NODES + v3[i]], 1)] = i;
  }
}

// ---------------- layernorm forward (bf16 G out) ----------------
__global__ __launch_bounds__(128) void k_layernorm(const float* X, const float* gamma, const float* beta,
                            bf16* Gb, float* mu, float* rstd, float* e_node){
  __shared__ float scr[2];
  int n = blockIdx.x, t = threadIdx.x;
  float x = X[(size_t)n * D_DIM + t];
  float sumx = bsum128(x, scr, t);
  float m = sumx * (1.0f / D_DIM);
  float xm = x - m;
  float var = bsum128(xm * xm, scr, t) * (1.0f / D_DIM);
  float rs = rsqrtf(var + 1e-5f);
  Gb[(size_t)n * D_DIM + t] = __float2bfloat16(gamma[t] * xm * rs + beta[t]);
  float sxx = bsum128(x * x, scr, t);
  if (t == 0){ mu[n] = m; rstd[n] = rs; e_node[n] = 0.5f * sxx; }
}

// ---------------- fwd GEMM via MFMA: P[n,f] = sum_d G[n,d]*Wcat[f,d] ----------------
__global__ __launch_bounds__(256) void k_fwd_mfma(const bf16* Gb, const bf16* wfF, bf16* P){
  int wave = threadIdx.x >> 6, lane = threadIdx.x & 63;
  int m0 = blockIdx.x * 64 + wave * 16;
  int tn0 = blockIdx.y * 8;          // 8 n-tiles of 16 -> N=128 per block
  int rw = lane & 15, quad = lane >> 4;
  const bf16* aptr = Gb + (size_t)(m0 + rw) * 128 + quad * 8;
  bf16x8 a[4];
#pragma unroll
  for (int kt = 0; kt < 4; kt++) a[kt] = *(const bf16x8*)(aptr + kt * 32);
  f32x4 acc[8];
#pragma unroll
  for (int i = 0; i < 8; i++) acc[i] = (f32x4){0.f, 0.f, 0.f, 0.f};
#pragma unroll
  for (int nf = 0; nf < 8; nf++){
    int tn = tn0 + nf;
#pragma unroll
    for (int kt = 0; kt < 4; kt++){
      bf16x8 b = *(const bf16x8*)(wfF + (((size_t)tn * 4 + kt) * 64 + lane) * 8);
      acc[nf] = __builtin_amdgcn_mfma_f32_16x16x32_bf16(a[kt], b, acc[nf], 0, 0, 0);
    }
  }
#pragma unroll
  for (int nf = 0; nf < 8; nf++){
    int col = (tn0 + nf) * 16 + rw;
#pragma unroll
    for (int r = 0; r < 4; r++){
      int row = m0 + quad * 4 + r;
      P[(size_t)row * F_TOT + col] = __float2bfloat16(acc[nf][r]);
    }
  }
}

// ---------------- bwd GEMM via MFMA: dG[n,d] = sum_f dP[n,f]*Wcat[f,d] ----------------
__global__ __launch_bounds__(256) void k_bwd_mfma(const bf16* dP, const bf16* wfB, float* dG){
  int wave = threadIdx.x >> 6, lane = threadIdx.x & 63;
  int m0 = blockIdx.x * 64 + wave * 16;
  int rw = lane & 15, quad = lane >> 4;
  const bf16* aptr = dP + (size_t)(m0 + rw) * F_TOT + quad * 8;
  f32x4 acc[8];
#pragma unroll
  for (int i = 0; i < 8; i++) acc[i] = (f32x4){0.f, 0.f, 0.f, 0.f};
  for (int kt = 0; kt < 28; kt++){
    bf16x8 a = *(const bf16x8*)(aptr + kt * 32);
#pragma unroll
    for (int td = 0; td < 8; td++){
      bf16x8 b = *(const bf16x8*)(wfB + (((size_t)td * 28 + kt) * 64 + lane) * 8);
      acc[td] = __builtin_amdgcn_mfma_f32_16x16x32_bf16(a, b, acc[td], 0, 0, 0);
    }
  }
#pragma unroll
  for (int td = 0; td < 8; td++){
    int col = td * 16 + rw;
#pragma unroll
    for (int r = 0; r < 4; r++){
      int row = m0 + quad * 4 + r;
      dG[(size_t)row * 128 + col] = acc[td][r];
    }
  }
}

// ---------------- edges: per-c online softmax + dQ2 (heads in wave halves) -------------
__global__ __launch_bounds__(256) void k_edge_c(const bf16* P, const int* u2, const float* a2,
                  const int* off, const int* lst, float* s2,
                  float* m2, float* z2, bf16* dP, float* e_node){
  int n = blockIdx.x * 4 + (threadIdx.x >> 6);
  int z = threadIdx.x & 63;
  int half = z >> 5;
  int beg = off[n], end = off[n + 1];
  unsigned qp = ((const unsigned*)(P + (size_t)n * F_TOT))[z];
  float qx = bflo(qp), qy = bfhi(qp);
  float mm = -INFINITY, zz = 0.f, accx = 0.f, accy = 0.f;
  for (int i = beg; i < end; i++){
    int e = lst[i];
    int u = u2[e];
    unsigned kp = ((const unsigned*)(P + (size_t)u * F_TOT + 128))[z];
    float kx = bflo(kp), ky = bfhi(kp);
    float s = hsum32(qx * kx + qy * ky) * 0.125f + a2[(size_t)e * 2 + half];
    if ((z & 31) == 0) s2[(size_t)e * 2 + half] = s;
    float mn = fmaxf(mm, s), sc = expf(mm - mn), ex = expf(s - mn);
    accx = accx * sc + ex * kx;  accy = accy * sc + ex * ky;
    zz = zz * sc + ex;  mm = mn;
  }
  float coef = (zz > 0.f) ? -0.125f / zz : 0.f;
  ((unsigned*)(dP + (size_t)n * F_TOT))[z] = packbf(coef * accx, coef * accy);
  float eterm = (zz > 0.f) ? -(mm + logf(zz)) : 0.f;
  float eo = __shfl(eterm, z ^ 32, 64);
  if (z == 0) e_node[n] += eterm + eo;                  // lam2 = 1
  if ((z & 31) == 0){ m2[n * 2 + half] = mm; z2[n * 2 + half] = zz; }
}

// scores -> probabilities in place
__global__ void k_p2(float* s2, const int* c2, const float* m2, const float* z2){
  int idx = blockIdx.x * 256 + threadIdx.x;
  if (idx >= E_EDG * 2) return;
  int e = idx >> 1, h = idx & 1;
  int c = c2[e];
  float zz = z2[c * 2 + h];
  s2[idx] = (zz > 0.f) ? expf(s2[idx] - m2[c * 2 + h]) / zz : 0.f;
}

// dK2[u] = -0.125 * sum p * Q2[c]
__global__ __launch_bounds__(256) void k_edge_u(const bf16* P, const int* c2, const float* p2,
                  const int* off, const int* lst, bf16* dP){
  int n = blockIdx.x * 4 + (threadIdx.x >> 6);
  int z = threadIdx.x & 63;
  int half = z >> 5;
  int beg = off[n], end = off[n + 1];
  float accx = 0.f, accy = 0.f;
  for (int i = beg; i < end; i++){
    int e = lst[i];
    int c = c2[e];
    unsigned qp = ((const unsigned*)(P + (size_t)c * F_TOT))[z];
    float p = p2[(size_t)e * 2 + half];
    accx += p * bflo(qp);  accy += p * bfhi(qp);
  }
  ((unsigned*)(dP + (size_t)n * F_TOT + 128))[z] = packbf(-0.125f * accx, -0.125f * accy);
}

// ---------------- motifs: per-c online softmax + dQ3 ((h,r) in 16-lane groups) --------
__global__ __launch_bounds__(256) void k_motif_c(const bf16* P, const int* u3, const int* v3,
                   const int* tt, const float* Ttau, const int* off, const int* lst,
                   float* s3, float* qkb, float* tvb, float* m3, float* z3,
                   bf16* dP, float* e_node){
  int n = blockIdx.x * 4 + (threadIdx.x >> 6);
  int z = threadIdx.x & 63;
  int grp = z >> 4, half = z >> 5;
  int beg = off[n], end = off[n + 1];
  uint2 qp = ((const uint2*)(P + (size_t)n * F_TOT + 256))[z];
  float q0 = bflo(qp.x), q1 = bfhi(qp.x), q2v = bflo(qp.y), q3v = bfhi(qp.y);
  float mm = -INFINITY, zz = 0.f;
  float a0 = 0.f, a1 = 0.f, a2v = 0.f, a3 = 0.f;
  for (int i = beg; i < end; i++){
    int m = lst[i];
    int u = u3[m], v = v3[m], t = tt[m];
    uint2 kup = ((const uint2*)(P + (size_t)u * F_TOT + 512))[z];
    uint2 kvp = ((const uint2*)(P + (size_t)v * F_TOT + 512))[z];
    float4 pt = ((const float4*)(Ttau + (size_t)t * 256))[z];
    float k0 = bflo(kup.x), k1 = bfhi(kup.x), k2 = bflo(kup.y), k3 = bfhi(kup.y);
    float v0 = bflo(kvp.x), v1 = bfhi(kvp.x), v2 = bflo(kvp.y), v3f = bfhi(kvp.y);
    float qk = hsum16(q0 * k0 + q1 * k1 + q2v * k2 + q3v * k3);
    float tv = hsum16(pt.x * v0 + pt.y * v1 + pt.z * v2 + pt.w * v3f);
    if ((z & 15) == 0){ qkb[(size_t)m * 4 + grp] = qk; tvb[(size_t)m * 4 + grp] = tv; }
    float w = qk * tv;
    float s = (w + __shfl_xor(w, 16, 64)) * (1.0f / 64.0f);
    if ((z & 31) == 0) s3[(size_t)m * 2 + half] = s;
    float mn = fmaxf(mm, s), sc = expf(mm - mn), ex = expf(s - mn);
    float et = ex * tv;
    a0 = a0 * sc + et * k0;  a1 = a1 * sc + et * k1;
    a2v = a2v * sc + et * k2;  a3 = a3 * sc + et * k3;
    zz = zz * sc + ex;  mm = mn;
  }
  const float cst = -0.5f / 64.0f;
  float coef = (zz > 0.f) ? cst / zz : 0.f;
  uint2 o;
  o.x = packbf(coef * a0, coef * a1);
  o.y = packbf(coef * a2v, coef * a3);
  ((uint2*)(dP + (size_t)n * F_TOT + 256))[z] = o;
  float eterm = (zz > 0.f) ? -0.5f * (mm + logf(zz)) : 0.f;   // lam3 = 0.5
  float eo = __shfl(eterm, z ^ 32, 64);
  if (z == 0) e_node[n] += eterm + eo;
  if ((z & 31) == 0){ m3[n * 2 + half] = mm; z3[n * 2 + half] = zz; }
}

__global__ void k_p3(float* s3, const int* c3, const float* m3, const float* z3){
  int idx = blockIdx.x * 256 + threadIdx.x;
  if (idx >= M_MOT * 2) return;
  int m = idx >> 1, h = idx & 1;
  int c = c3[m];
  float zz = z3[c * 2 + h];
  s3[idx] = (zz > 0.f) ? expf(s3[idx] - m3[c * 2 + h]) / zz : 0.f;
}

// dK3[n] from u-role and v-role contributions
__global__ __launch_bounds__(256) void k_motif_uv(const bf16* P, const int* c3, const int* tt,
                    const float* Ttau, const float* p3, const float* qkb, const float* tvb,
                    const int* offu, const int* lstu, const int* offv, const int* lstv, bf16* dP){
  int n = blockIdx.x * 4 + (threadIdx.x >> 6);
  int z = threadIdx.x & 63;
  int grp = z >> 4, half = z >> 5;
  float a0 = 0.f, a1 = 0.f, a2v = 0.f, a3 = 0.f;
  int beg = offu[n], end = offu[n + 1];
  for (int i = beg; i < end; i++){
    int m = lstu[i];
    int c = c3[m];
    uint2 qp = ((const uint2*)(P + (size_t)c * F_TOT + 256))[z];
    float w = p3[(size_t)m * 2 + half] * tvb[(size_t)m * 4 + grp];
    a0 += w * bflo(qp.x);  a1 += w * bfhi(qp.x);
    a2v += w * bflo(qp.y);  a3 += w * bfhi(qp.y);
  }
  beg = offv[n]; end = offv[n + 1];
  for (int i = beg; i < end; i++){
    int m = lstv[i];
    int t = tt[m];
    float4 pt = ((const float4*)(Ttau + (size_t)t * 256))[z];
    float w = p3[(size_t)m * 2 + half] * qkb[(size_t)m * 4 + grp];
    a0 += w * pt.x;  a1 += w * pt.y;  a2v += w * pt.z;  a3 += w * pt.w;
  }
  const float cst = -0.5f / 64.0f;
  uint2 o;
  o.x = packbf(cst * a0, cst * a1);
  o.y = packbf(cst * a2v, cst * a3);
  ((uint2*)(dP + (size_t)n * F_TOT + 512))[z] = o;
}

// ---------------- memory term: forward + backward fused (node-local) ----------------
__global__ __launch_bounds__(64) void k_mem(const bf16* P, const float* Km, bf16* dP, float* e_node){
  __shared__ float Qs[128];
  __shared__ float pmem[64];
  __shared__ float em[2];
  int n = blockIdx.x, t = threadIdx.x;
  Qs[t]      = __bfloat162float(P[(size_t)n * F_TOT + 768 + t]);
  Qs[t + 64] = __bfloat162float(P[(size_t)n * F_TOT + 768 + t + 64]);
  __syncthreads();
  int h = t >> 5, k = t & 31;
  const float* km = Km + h * 2048 + k * 64;
  const float* qs = Qs + h * 64;
  float acc = 0.f;
  for (int z = 0; z < 64; z++) acc += qs[z] * km[z];
  float sm = acc * 0.125f;
  float mx = sm;
#pragma unroll
  for (int o = 16; o > 0; o >>= 1) mx = fmaxf(mx, __shfl_xor(mx, o, 64));
  float ex = expf(sm - mx);
  float se = ex;
#pragma unroll
  for (int o = 16; o > 0; o >>= 1) se += __shfl_xor(se, o, 64);
  pmem[t] = ex / se;
  if (k == 0) em[h] = -(mx + logf(se));
  __syncthreads();
#pragma unroll
  for (int pass = 0; pass < 2; pass++){
    int idx = pass * 64 + t;
    int h2 = idx >> 6, zc = idx & 63;
    const float* km2 = Km + h2 * 2048;
    const float* ph = pmem + h2 * 32;
    float a = 0.f;
    for (int kk = 0; kk < 32; kk++) a += ph[kk] * km2[kk * 64 + zc];
    dP[(size_t)n * F_TOT + 768 + idx] = __float2bfloat16(-0.125f * a);
  }
  if (t == 0) e_node[n] += em[0] + em[1];
}

// ---------------- per-graph energy sum ----------------
__global__ __launch_bounds__(256) void k_node_energy(const float* e_node, const int* batch, float* Eg){
  __shared__ float eg[NG_G];
  int t = threadIdx.x;
  if (t < NG_G) eg[t] = 0.f;
  __syncthreads();
  int n = blockIdx.x * 256 + t;
  atomicAdd(&eg[batch[n]], e_node[n]);
  __syncthreads();
  if (t < NG_G) atomicAdd(&Eg[t], eg[t]);
}

// ---------------- finalize: LN backward + clip + step + state clip ----------------
__global__ __launch_bounds__(128) void k_finalize(const float* X, const float* dG, const float* gamma,
                    const float* mu, const float* rstd, const float* step_p, float* out){
  __shared__ float scr[2];
  int n = blockIdx.x, t = threadIdx.x;
  float x = X[(size_t)n * 128 + t];
  float dg = dG[(size_t)n * 128 + t];
  float gam = gamma[t];
  float rs = rstd[n];
  float xhat = (x - mu[n]) * rs;
  float dxh = dg * gam;
  float s1 = bsum128(dxh, scr, t);
  float s2v = bsum128(dxh * xhat, scr, t);
  float dx = rs * (dxh - s1 * (1.0f / 128) - xhat * (s2v * (1.0f / 128)));
  float g = x + dx;
  float gn = sqrtf(bsum128(g * g, scr, t));
  g *= 1.0f / fmaxf(gn, 1.0f);
  float step = step_p[0];
  float xn = x - step * g;
  float sn = sqrtf(bsum128(xn * xn, scr, t));
  xn *= 10.0f / fmaxf(sn, 10.0f);
  out[(size_t)n * 128 + t] = xn;
}

__global__ void k_write_eg(const float* Eg, float* out){
  int t = threadIdx.x;
  if (t < NG_G) out[(size_t)N_NODES * 128 + t] = Eg[t];
}

extern "C" void kernel_launch(void* const* d_in, const int* in_sizes, int n_in,
                              void* d_out, int out_size, void* d_ws, size_t ws_size,
                              hipStream_t stream) {
  const float* X     = (const float*)d_in[0];
  const int*  c_2    = (const int*) d_in[1];
  const int*  u_2    = (const int*) d_in[2];
  const int*  c_3    = (const int*) d_in[3];
  const int*  u_3    = (const int*) d_in[4];
  const int*  v_3    = (const int*) d_in[5];
  const int*  t_tau  = (const int*) d_in[6];
  const int*  batch  = (const int*) d_in[7];
  const float* a_2   = (const float*)d_in[8];
  const float* step_s= (const float*)d_in[9];
  const float* ln_g  = (const float*)d_in[10];
  const float* ln_b  = (const float*)d_in[11];
  const float* W_Q2  = (const float*)d_in[12];
  const float* W_K2  = (const float*)d_in[13];
  const float* W_Q3  = (const float*)d_in[14];
  const float* W_K3  = (const float*)d_in[15];
  const float* T_tau = (const float*)d_in[16];
  const float* W_Qm  = (const float*)d_in[17];
  const float* W_Km  = (const float*)d_in[18];
  const float* B_mem = (const float*)d_in[19];
  float* out = (float*)d_out;

  char* wb = (char*)d_ws;
  float* Wcat   = (float*)wb; wb += F_TOT * D_DIM * 4;
  float* Km     = (float*)wb; wb += 4096 * 4;
  float* mu     = (float*)wb; wb += N_NODES * 4;
  float* rstd   = (float*)wb; wb += N_NODES * 4;
  float* s2     = (float*)wb; wb += (size_t)E_EDG * 2 * 4;
  float* m2     = (float*)wb; wb += N_NODES * 2 * 4;
  float* z2     = (float*)wb; wb += N_NODES * 2 * 4;
  float* s3     = (float*)wb; wb += (size_t)M_MOT * 2 * 4;
  float* qkb    = (float*)wb; wb += (size_t)M_MOT * 4 * 4;
  float* tvb    = (float*)wb; wb += (size_t)M_MOT * 4 * 4;
  float* m3     = (float*)wb; wb += N_NODES * 2 * 4;
  float* z3     = (float*)wb; wb += N_NODES * 2 * 4;
  float* e_node = (float*)wb; wb += N_NODES * 4;
  float* Eg     = (float*)wb; wb += NG_G * 4;
  float* dG     = (float*)wb; wb += (size_t)N_NODES * D_DIM * 4;
  bf16* Gb      = (bf16*)wb;  wb += (size_t)N_NODES * D_DIM * 2;
  bf16* P       = (bf16*)wb;  wb += (size_t)N_NODES * F_TOT * 2;
  bf16* dP      = (bf16*)wb;  wb += (size_t)N_NODES * F_TOT * 2;
  bf16* wfF     = (bf16*)wb;  wb += 114688 * 2;
  bf16* wfB     = (bf16*)wb;  wb += 114688 * 2;
  int* cntcur   = (int*)wb;   wb += 5 * N_NODES * 4;
  int* off      = (int*)wb;   wb += 5 * (N_NODES + 1) * 4;
  int* lec      = (int*)wb;   wb += E_EDG * 4;
  int* leu      = (int*)wb;   wb += E_EDG * 4;
  int* lmc      = (int*)wb;   wb += M_MOT * 4;
  int* lmu      = (int*)wb;   wb += M_MOT * 4;
  int* lmv      = (int*)wb;   wb += M_MOT * 4;

  const int* off_ec = off;
  const int* off_eu = off + (N_NODES + 1);
  const int* off_mc = off + 2 * (N_NODES + 1);
  const int* off_mu = off + 3 * (N_NODES + 1);
  const int* off_mv = off + 4 * (N_NODES + 1);

  hipLaunchKernelGGL(k_zero, dim3((5 * N_NODES + 255) / 256), dim3(256), 0, stream, cntcur, Eg);
  hipLaunchKernelGGL(k_prep_wcat, dim3((F_TOT * D_DIM + 255) / 256), dim3(256), 0, stream,
                     W_Q2, W_K2, W_Q3, W_K3, W_Qm, Wcat);
  hipLaunchKernelGGL(k_pack_frags, dim3((114688 + 255) / 256), dim3(256), 0, stream, Wcat, wfF, wfB);
  hipLaunchKernelGGL(k_prep_km, dim3(16), dim3(256), 0, stream, W_Km, B_mem, Km);
  hipLaunchKernelGGL(k_hist, dim3((E_EDG + 255) / 256), dim3(256), 0, stream,
                     c_2, u_2, c_3, u_3, v_3, cntcur);
  hipLaunchKernelGGL(k_scan, dim3(5), dim3(1024), 0, stream, cntcur, off);
  hipLaunchKernelGGL(k_fill, dim3((E_EDG + 255) / 256), dim3(256), 0, stream,
                     c_2, u_2, c_3, u_3, v_3, cntcur, lec, leu, lmc, lmu, lmv);
  hipLaunchKernelGGL(k_layernorm, dim3(N_NODES), dim3(128), 0, stream, X, ln_g, ln_b, Gb, mu, rstd, e_node);
  hipLaunchKernelGGL(k_fwd_mfma, dim3(N_NODES / 64, 7), dim3(256), 0, stream, Gb, wfF, P);
  hipLaunchKernelGGL(k_edge_c, dim3(N_NODES / 4), dim3(256), 0, stream,
                     P, u_2, a_2, off_ec, lec, s2, m2, z2, dP, e_node);
  hipLaunchKernelGGL(k_p2, dim3((E_EDG * 2 + 255) / 256), dim3(256), 0, stream, s2, c_2, m2, z2);
  hipLaunchKernelGGL(k_edge_u, dim3(N_NODES / 4), dim3(256), 0, stream, P, c_2, s2, off_eu, leu, dP);
  hipLaunchKernelGGL(k_motif_c, dim3(N_NODES / 4), dim3(256), 0, stream,
                     P, u_3, v_3, t_tau, T_tau, off_mc, lmc, s3, qkb, tvb, m3, z3, dP, e_node);
  hipLaunchKernelGGL(k_p3, dim3((M_MOT * 2 + 255) / 256), dim3(256), 0, stream, s3, c_3, m3, z3);
  hipLaunchKernelGGL(k_motif_uv, dim3(N_NODES / 4), dim3(256), 0, stream,
                     P, c_3, t_tau, T_tau, s3, qkb, tvb, off_mu, lmu, off_mv, lmv, dP);
  hipLaunchKernelGGL(k_mem, dim3(N_NODES), dim3(64), 0, stream, P, Km, dP, e_node);
  hipLaunchKernelGGL(k_node_energy, dim3(N_NODES / 256), dim3(256), 0, stream, e_node, batch, Eg);
  hipLaunchKernelGGL(k_bwd_mfma, dim3(N_NODES / 64), dim3(256), 0, stream, dP, wfB, dG);
  hipLaunchKernelGGL(k_finalize, dim3(N_NODES), dim3(128), 0, stream, X, dG, ln_g, mu, rstd, step_s, out);
  hipLaunchKernelGGL(k_write_eg, dim3(1), dim3(64), 0, stream, Eg, out);
}